// Round 1
// baseline (430.468 us; speedup 1.0000x reference)
//
#include <hip/hip_runtime.h>
#include <math.h>

#define LAYERS 6
#define BATCH 128
#define NQ 2000
#define NC 3
#define NP 20
#define TOPK 100
#define QC (NQ * NC) /* 6000 */
#define NTHREADS 256

// Output layout (float32, concatenated flat in reference return order):
//   boxes  [128,100,4]    @ 0       (51200)
//   scores [128,100]      @ 51200   (12800)
//   labels [128,100]      @ 64000   (12800)  (stored as float: -1,0,1,2)
//   pts    [128,100,20,2] @ 76800   (512000)
//   mask   [128,100]      @ 588800  (12800)  (stored as float 0/1)
#define BOXES_OFF 0
#define SCORES_OFF 51200
#define LABELS_OFF 64000
#define PTS_OFF 76800
#define MASK_OFF 588800

__global__ __launch_bounds__(NTHREADS) void maptr_post_kernel(
    const float* __restrict__ cls,   // last layer [B,Q,C]
    const float* __restrict__ bbox,  // last layer [B,Q,4]
    const float* __restrict__ pts,   // last layer [B,Q,P,2]
    float* __restrict__ out)
{
    const int b = blockIdx.x;
    const int tid = threadIdx.x;
    const int lane = tid & 63;
    const int wid = tid >> 6;

    __shared__ float svals[QC];
    __shared__ float swv[4];
    __shared__ int swi[4];
    __shared__ float topv[TOPK];
    __shared__ int topi[TOPK];
    __shared__ int sbi[TOPK];
    __shared__ float smask[TOPK];

    // Stage logits for this batch into LDS (sigmoid is monotone: select on logits).
    const float* clsb = cls + (size_t)b * QC;
    for (int i = tid; i < QC; i += NTHREADS) svals[i] = clsb[i];
    __syncthreads();

    // Per-thread running best over its strided slice (smallest index wins ties:
    // ascending scan + strict '>' keeps the first/lowest index).
    float myv = -INFINITY;
    int myi = 0x7fffffff;
    for (int i = tid; i < QC; i += NTHREADS) {
        float v = svals[i];
        if (v > myv) { myv = v; myi = i; }
    }

    // 100 rounds of block argmax; only the winner's owner thread rescans.
    for (int m = 0; m < TOPK; ++m) {
        float v = myv;
        int ii = myi;
        #pragma unroll
        for (int off = 32; off > 0; off >>= 1) {
            float ov = __shfl_down(v, off);
            int oi = __shfl_down(ii, off);
            if (ov > v || (ov == v && oi < ii)) { v = ov; ii = oi; }
        }
        if (lane == 0) { swv[wid] = v; swi[wid] = ii; }
        __syncthreads();
        float wv = swv[0];
        int wi = swi[0];
        #pragma unroll
        for (int w = 1; w < 4; ++w) {
            float ov = swv[w];
            int oi = swi[w];
            if (ov > wv || (ov == wv && oi < wi)) { wv = ov; wi = oi; }
        }
        if (tid == 0) { topv[m] = wv; topi[m] = wi; }
        if ((wi & (NTHREADS - 1)) == tid) {
            // I own the winner: remove it and recompute my local best.
            svals[wi] = -INFINITY;
            myv = -INFINITY;
            myi = 0x7fffffff;
            for (int i = tid; i < QC; i += NTHREADS) {
                float vv = svals[i];
                if (vv > myv) { myv = vv; myi = i; }
            }
        }
        __syncthreads();
    }

    float* const boxes_out = out + BOXES_OFF;
    float* const scores_out = out + SCORES_OFF;
    float* const labels_out = out + LABELS_OFF;
    float* const pts_out = out + PTS_OFF;
    float* const mask_out = out + MASK_OFF;

    // Decode boxes / scores / labels / mask (threads 0..99).
    if (tid < TOPK) {
        const int m = tid;
        const int idx = topi[m];
        const float lv = topv[m];
        const float score = 1.0f / (1.0f + expf(-lv));
        const int bi = idx / 3;
        const int label = idx - bi * 3;

        const float4 bb = *(const float4*)(bbox + ((size_t)b * NQ + bi) * 4);
        const float x1 = bb.x - 0.5f * bb.z;
        const float y1 = bb.y - 0.5f * bb.w;
        const float x2 = bb.x + 0.5f * bb.z;
        const float y2 = bb.y + 0.5f * bb.w;
        const float bx1 = x1 * 30.0f + (-15.0f);
        const float by1 = y1 * 60.0f + (-30.0f);
        const float bx2 = x2 * 30.0f + (-15.0f);
        const float by2 = y2 * 60.0f + (-30.0f);

        const bool mk = (bx1 >= -20.0f) && (by1 >= -35.0f) && (bx2 >= -20.0f) && (by2 >= -35.0f) &&
                        (bx1 <= 20.0f) && (by1 <= 35.0f) && (bx2 <= 20.0f) && (by2 <= 35.0f);

        const size_t bm = (size_t)b * TOPK + m;
        boxes_out[bm * 4 + 0] = mk ? bx1 : 0.0f;
        boxes_out[bm * 4 + 1] = mk ? by1 : 0.0f;
        boxes_out[bm * 4 + 2] = mk ? bx2 : 0.0f;
        boxes_out[bm * 4 + 3] = mk ? by2 : 0.0f;
        scores_out[bm] = mk ? score : 0.0f;
        labels_out[bm] = mk ? (float)label : -1.0f;
        mask_out[bm] = mk ? 1.0f : 0.0f;
        sbi[m] = bi;
        smask[m] = mk ? 1.0f : 0.0f;
    }
    __syncthreads();

    // Decode points: 100 * 20 = 2000 (m,p) tasks.
    for (int t = tid; t < TOPK * NP; t += NTHREADS) {
        const int m = t / NP;
        const int p = t - m * NP;
        const int bi = sbi[m];
        const bool mk = smask[m] != 0.0f;
        const float2 pv = *(const float2*)(pts + (((size_t)b * NQ + bi) * NP + p) * 2);
        const float ox = mk ? (pv.x * 30.0f + (-15.0f)) : 0.0f;
        const float oy = mk ? (pv.y * 60.0f + (-30.0f)) : 0.0f;
        const size_t o = (((size_t)b * TOPK + m) * NP + p) * 2;
        pts_out[o + 0] = ox;
        pts_out[o + 1] = oy;
    }
}

extern "C" void kernel_launch(void* const* d_in, const int* in_sizes, int n_in,
                              void* d_out, int out_size, void* d_ws, size_t ws_size,
                              hipStream_t stream) {
    const float* cls = (const float*)d_in[0] + (size_t)(LAYERS - 1) * BATCH * NQ * NC;
    const float* bbox = (const float*)d_in[1] + (size_t)(LAYERS - 1) * BATCH * NQ * 4;
    const float* pts = (const float*)d_in[2] + (size_t)(LAYERS - 1) * BATCH * NQ * NP * 2;
    maptr_post_kernel<<<BATCH, NTHREADS, 0, stream>>>(cls, bbox, pts, (float*)d_out);
}

// Round 2
// 313.164 us; speedup vs baseline: 1.3746x; 1.3746x over previous
//
#include <hip/hip_runtime.h>
#include <math.h>

#define LAYERS 6
#define BATCH 128
#define NQ 2000
#define NC 3
#define NP 20
#define TOPK 100
#define QC (NQ * NC) /* 6000 */
#define NTHREADS 256
#define TIE_CAP 256

// Output layout (float32, flat in reference return order):
//   boxes  [128,100,4]    @ 0       (51200)
//   scores [128,100]      @ 51200   (12800)
//   labels [128,100]      @ 64000   (12800)
//   pts    [128,100,20,2] @ 76800   (512000)
//   mask   [128,100]      @ 588800  (12800)
#define BOXES_OFF 0
#define SCORES_OFF 51200
#define LABELS_OFF 64000
#define PTS_OFF 76800
#define MASK_OFF 588800

__global__ __launch_bounds__(NTHREADS) void maptr_post_kernel(
    const float* __restrict__ cls,   // last layer [B,Q,C]
    const float* __restrict__ bbox,  // last layer [B,Q,4]
    const float* __restrict__ pts,   // last layer [B,Q,P,2]
    float* __restrict__ out)
{
    const int b = blockIdx.x;
    const int tid = threadIdx.x;

    __shared__ unsigned int su[QC];       // order-preserving keys
    __shared__ int hist[256];
    __shared__ int scanb[256];
    __shared__ unsigned int cand_u[TOPK];
    __shared__ int cand_i[TOPK];
    __shared__ int tie_i[TIE_CAP];
    __shared__ int sT, sGt, nCand, nTie;
    __shared__ float topv[TOPK];
    __shared__ int topi[TOPK];
    __shared__ int sbi[TOPK];
    __shared__ float smask[TOPK];

    if (tid == 0) { nCand = 0; nTie = 0; }

    // Load logits, convert to order-preserving uint (sigmoid monotone -> select on logits).
    const float* clsb = cls + (size_t)b * QC;
    for (int i = tid; i < QC; i += NTHREADS) {
        unsigned int bits = __float_as_uint(clsb[i]);
        su[i] = (bits & 0x80000000u) ? ~bits : (bits | 0x80000000u);
    }
    __syncthreads();

    // 4-pass radix select: find exact 32-bit key of the 100th largest.
    unsigned int prefix = 0, pmask = 0;
    int need = TOPK;
    #pragma unroll
    for (int pass = 0; pass < 4; ++pass) {
        const int shift = 24 - 8 * pass;
        hist[tid] = 0;
        __syncthreads();
        for (int i = tid; i < QC; i += NTHREADS) {
            unsigned int u = su[i];
            if ((u & pmask) == prefix)
                atomicAdd(&hist[(u >> shift) & 0xffu], 1);
        }
        __syncthreads();
        scanb[tid] = hist[tid];
        __syncthreads();
        // Hillis-Steele inclusive suffix sum: scanb[t] = count(byte >= t)
        #pragma unroll
        for (int off = 1; off < 256; off <<= 1) {
            int add = (tid + off < 256) ? scanb[tid + off] : 0;
            __syncthreads();
            scanb[tid] += add;
            __syncthreads();
        }
        // Unique t with scanb[t] >= need > scanb[t+1]
        if (scanb[tid] >= need && (tid == 255 || scanb[tid + 1] < need)) {
            sT = tid;
            sGt = (tid == 255) ? 0 : scanb[tid + 1];
        }
        __syncthreads();
        prefix |= ((unsigned int)sT) << shift;
        pmask |= 0xffu << shift;
        need -= sGt;   // slots left for keys <= current refined prefix
        __syncthreads();
    }
    const unsigned int T32 = prefix;   // exact 100th-largest key
    const int R = need;                // # ties (key == T32) to admit, by smallest index

    // Collect strict-greaters (count G < 100) and tie indices.
    for (int i = tid; i < QC; i += NTHREADS) {
        unsigned int u = su[i];
        if (u > T32) {
            int p = atomicAdd(&nCand, 1);
            cand_u[p] = u; cand_i[p] = i;
        } else if (u == T32) {
            int p = atomicAdd(&nTie, 1);
            if (p < TIE_CAP) tie_i[p] = i;
        }
    }
    __syncthreads();
    const int G = nCand;
    const int E = (nTie < TIE_CAP) ? nTie : TIE_CAP;
    // Admit the R smallest-index ties into slots G..G+R-1 (index-ascending).
    if (tid < E) {
        int mine = tie_i[tid];
        int rk = 0;
        for (int j = 0; j < E; ++j) rk += (tie_i[j] < mine);
        if (rk < R) { cand_u[G + rk] = T32; cand_i[G + rk] = mine; }
    }
    __syncthreads();

    // Rank the 100 selected: descending key, ascending index on ties (top_k order).
    if (tid < TOPK) {
        unsigned int u = cand_u[tid];
        int ii = cand_i[tid];
        int rank = 0;
        for (int j = 0; j < TOPK; ++j) {
            unsigned int uj = cand_u[j];
            int ij = cand_i[j];
            rank += (uj > u) || (uj == u && ij < ii);
        }
        unsigned int bits = (u & 0x80000000u) ? (u & 0x7fffffffu) : ~u;
        topv[rank] = __uint_as_float(bits);
        topi[rank] = ii;
    }
    __syncthreads();

    float* const boxes_out = out + BOXES_OFF;
    float* const scores_out = out + SCORES_OFF;
    float* const labels_out = out + LABELS_OFF;
    float* const pts_out = out + PTS_OFF;
    float* const mask_out = out + MASK_OFF;

    if (tid < TOPK) {
        const int m = tid;
        const int idx = topi[m];
        const float lv = topv[m];
        const float score = 1.0f / (1.0f + expf(-lv));
        const int bi = idx / 3;
        const int label = idx - bi * 3;

        const float4 bb = *(const float4*)(bbox + ((size_t)b * NQ + bi) * 4);
        const float bx1 = (bb.x - 0.5f * bb.z) * 30.0f - 15.0f;
        const float by1 = (bb.y - 0.5f * bb.w) * 60.0f - 30.0f;
        const float bx2 = (bb.x + 0.5f * bb.z) * 30.0f - 15.0f;
        const float by2 = (bb.y + 0.5f * bb.w) * 60.0f - 30.0f;

        const bool mk = (bx1 >= -20.0f) && (by1 >= -35.0f) && (bx2 >= -20.0f) && (by2 >= -35.0f) &&
                        (bx1 <= 20.0f) && (by1 <= 35.0f) && (bx2 <= 20.0f) && (by2 <= 35.0f);

        const size_t bm = (size_t)b * TOPK + m;
        boxes_out[bm * 4 + 0] = mk ? bx1 : 0.0f;
        boxes_out[bm * 4 + 1] = mk ? by1 : 0.0f;
        boxes_out[bm * 4 + 2] = mk ? bx2 : 0.0f;
        boxes_out[bm * 4 + 3] = mk ? by2 : 0.0f;
        scores_out[bm] = mk ? score : 0.0f;
        labels_out[bm] = mk ? (float)label : -1.0f;
        mask_out[bm] = mk ? 1.0f : 0.0f;
        sbi[m] = bi;
        smask[m] = mk ? 1.0f : 0.0f;
    }
    __syncthreads();

    // Points: 100*20 = 2000 (m,p) tasks.
    for (int t = tid; t < TOPK * NP; t += NTHREADS) {
        const int m = t / NP;
        const int p = t - m * NP;
        const int bi = sbi[m];
        const bool mk = smask[m] != 0.0f;
        const float2 pv = *(const float2*)(pts + (((size_t)b * NQ + bi) * NP + p) * 2);
        const size_t o = (((size_t)b * TOPK + m) * NP + p) * 2;
        pts_out[o + 0] = mk ? (pv.x * 30.0f - 15.0f) : 0.0f;
        pts_out[o + 1] = mk ? (pv.y * 60.0f - 30.0f) : 0.0f;
    }
}

extern "C" void kernel_launch(void* const* d_in, const int* in_sizes, int n_in,
                              void* d_out, int out_size, void* d_ws, size_t ws_size,
                              hipStream_t stream) {
    const float* cls = (const float*)d_in[0] + (size_t)(LAYERS - 1) * BATCH * NQ * NC;
    const float* bbox = (const float*)d_in[1] + (size_t)(LAYERS - 1) * BATCH * NQ * 4;
    const float* pts = (const float*)d_in[2] + (size_t)(LAYERS - 1) * BATCH * NQ * NP * 2;
    maptr_post_kernel<<<BATCH, NTHREADS, 0, stream>>>(cls, bbox, pts, (float*)d_out);
}